// Round 1
// baseline (634.087 us; speedup 1.0000x reference)
//
#include <hip/hip_runtime.h>

#define DDIM 128

// Kernel 1: z_i = a*z1 + b*z2  (store to ws), out = (1-alpha)*z_i  (init)
__global__ void __launch_bounds__(256) fuse_zi_kernel(
    const float4* __restrict__ z1, const float4* __restrict__ z2,
    const float4* __restrict__ a,  const float4* __restrict__ b,
    const float* __restrict__ alpha_p,
    float4* __restrict__ zi, float4* __restrict__ out, int n4) {
  const float alpha = alpha_p[0];
  const float one_m = 1.0f - alpha;
  int i = blockIdx.x * blockDim.x + threadIdx.x;
  const int stride = gridDim.x * blockDim.x;
  for (; i < n4; i += stride) {
    float4 A = a[i], B = b[i], Z1 = z1[i], Z2 = z2[i];
    float4 z;
    z.x = A.x * Z1.x + B.x * Z2.x;
    z.y = A.y * Z1.y + B.y * Z2.y;
    z.z = A.z * Z1.z + B.z * Z2.z;
    z.w = A.w * Z1.w + B.w * Z2.w;
    zi[i] = z;
    float4 o;
    o.x = one_m * z.x; o.y = one_m * z.y;
    o.z = one_m * z.z; o.w = one_m * z.w;
    out[i] = o;
  }
}

// Kernel 2: one wave per edge. out[row[e]] += alpha*val[e] * z_i[col[e]]
__global__ void __launch_bounds__(256) scatter_kernel(
    const int* __restrict__ rows, const int* __restrict__ cols,
    const float* __restrict__ vals, const float* __restrict__ alpha_p,
    const float* __restrict__ zi, float* __restrict__ out, int E) {
  const unsigned tid = blockIdx.x * blockDim.x + threadIdx.x;
  const int wid = (int)(tid >> 6);          // one wave per edge
  const int lane = threadIdx.x & 63;
  if (wid >= E) return;
  const int r = rows[wid];                  // broadcast loads (same addr per wave)
  const int c = cols[wid];
  const float av = alpha_p[0] * vals[wid];
  const float2 v =
      reinterpret_cast<const float2*>(zi + (size_t)c * DDIM)[lane];
  float* dst = out + (size_t)r * DDIM + lane * 2;
  unsafeAtomicAdd(dst,     av * v.x);       // global_atomic_add_f32, no CAS
  unsafeAtomicAdd(dst + 1, av * v.y);
}

extern "C" void kernel_launch(void* const* d_in, const int* in_sizes, int n_in,
                              void* d_out, int out_size, void* d_ws, size_t ws_size,
                              hipStream_t stream) {
  const float* z1    = (const float*)d_in[0];
  const float* z2    = (const float*)d_in[1];
  const int*   rows  = (const int*)  d_in[2];
  const int*   cols  = (const int*)  d_in[3];
  const float* vals  = (const float*)d_in[4];
  const float* a     = (const float*)d_in[5];
  const float* b     = (const float*)d_in[6];
  const float* alpha = (const float*)d_in[7];
  float* out = (float*)d_out;
  float* zi  = (float*)d_ws;               // N*D floats = 25.6 MB scratch

  const int ND = in_sizes[0];              // N*D
  const int E  = in_sizes[2];
  const int n4 = ND / 4;

  int blocks1 = (n4 + 255) / 256;
  if (blocks1 > 2048) blocks1 = 2048;      // grid-stride
  fuse_zi_kernel<<<blocks1, 256, 0, stream>>>(
      (const float4*)z1, (const float4*)z2, (const float4*)a,
      (const float4*)b, alpha, (float4*)zi, (float4*)out, n4);

  const long long threads2 = (long long)E * 64;
  const int blocks2 = (int)((threads2 + 255) / 256);
  scatter_kernel<<<blocks2, 256, 0, stream>>>(
      rows, cols, vals, alpha, zi, out, E);
}

// Round 2
// 240.506 us; speedup vs baseline: 2.6365x; 2.6365x over previous
//
#include <hip/hip_runtime.h>

#define DDIM 128

// Phase A: zi = a*z1 + b*z2 (float4, grid-stride)
// Phase B: bucket edges into per-row linked lists:
//          next[e] = atomicExch(&head[rows[e]], e)
// (phases independent; fused to save a launch)
__global__ void __launch_bounds__(256) build_kernel(
    const float4* __restrict__ z1, const float4* __restrict__ z2,
    const float4* __restrict__ a,  const float4* __restrict__ b,
    float4* __restrict__ zi, int n4,
    const int* __restrict__ rows, int* __restrict__ head,
    int* __restrict__ next, int E) {
  const int i = blockIdx.x * blockDim.x + threadIdx.x;
  const int stride = gridDim.x * blockDim.x;
  for (int j = i; j < n4; j += stride) {
    float4 A = a[j], B = b[j], X = z1[j], Y = z2[j];
    float4 z;
    z.x = A.x * X.x + B.x * Y.x;
    z.y = A.y * X.y + B.y * Y.y;
    z.z = A.z * X.z + B.z * Y.z;
    z.w = A.w * X.w + B.w * Y.w;
    zi[j] = z;
  }
  for (int e = i; e < E; e += stride) {
    next[e] = atomicExch(&head[rows[e]], e);
  }
}

// One wave per output row: walk the row's edge list, gather+accumulate in
// registers (float2 per lane), write the row once with residual blend fused.
__global__ void __launch_bounds__(256) reduce_kernel(
    const int* __restrict__ head, const int* __restrict__ next,
    const int* __restrict__ cols, const float* __restrict__ vals,
    const float* __restrict__ alpha_p,
    const float2* __restrict__ zi2, float2* __restrict__ out2, int N) {
  const int wid = (int)((blockIdx.x * blockDim.x + threadIdx.x) >> 6);
  const int lane = threadIdx.x & 63;
  if (wid >= N) return;
  const float alpha = alpha_p[0];

  float2 acc = make_float2(0.f, 0.f);
  int e = head[wid];
  while (e >= 0) {
    const int en = next[e];        // issue chase early
    const int c = cols[e];
    const float v = vals[e];
    const float2 g = zi2[(size_t)c * (DDIM / 2) + lane];
    acc.x += v * g.x;
    acc.y += v * g.y;
    e = en;
  }

  const float2 zr = zi2[(size_t)wid * (DDIM / 2) + lane];
  const float om = 1.0f - alpha;
  float2 o;
  o.x = alpha * acc.x + om * zr.x;
  o.y = alpha * acc.y + om * zr.y;
  out2[(size_t)wid * (DDIM / 2) + lane] = o;
}

extern "C" void kernel_launch(void* const* d_in, const int* in_sizes, int n_in,
                              void* d_out, int out_size, void* d_ws, size_t ws_size,
                              hipStream_t stream) {
  const float* z1    = (const float*)d_in[0];
  const float* z2    = (const float*)d_in[1];
  const int*   rows  = (const int*)  d_in[2];
  const int*   cols  = (const int*)  d_in[3];
  const float* vals  = (const float*)d_in[4];
  const float* a     = (const float*)d_in[5];
  const float* b     = (const float*)d_in[6];
  const float* alpha = (const float*)d_in[7];
  float* out = (float*)d_out;

  const int ND = in_sizes[0];          // N*D
  const int E  = in_sizes[2];
  const int N  = ND / DDIM;
  const int n4 = ND / 4;

  // workspace layout (floats/ints, all 4-byte):
  //   zi   : ND floats          (25.6 MB)
  //   head : N  ints            (0.2 MB)
  //   next : E  ints            (2.4 MB)
  float* zi  = (float*)d_ws;
  int* head  = (int*)(zi + ND);
  int* next  = head + N;

  hipMemsetAsync(head, 0xFF, (size_t)N * sizeof(int), stream);  // head = -1

  const int blocks1 = 2048;            // grid-stride covers n4 (1.6M) and E
  build_kernel<<<blocks1, 256, 0, stream>>>(
      (const float4*)z1, (const float4*)z2, (const float4*)a,
      (const float4*)b, (float4*)zi, n4, rows, head, next, E);

  const int blocks2 = (N * 64 + 255) / 256;   // one wave per row
  reduce_kernel<<<blocks2, 256, 0, stream>>>(
      head, next, cols, vals, alpha, (const float2*)zi, (float2*)out, N);
}

// Round 3
// 212.621 us; speedup vs baseline: 2.9822x; 1.1311x over previous
//
#include <hip/hip_runtime.h>

#define DDIM 128
#define CAPMAX 32

// Fused: (A) zi = a*z1 + b*z2  (float4, grid-stride)
//        (B) padded-CSR build: slot j = atomicAdd(cnt[row]); if j<cap store
//            (col,val) into slots[row*cap+j]; else push e onto overflow chain.
__global__ void __launch_bounds__(256) build_kernel(
    const float4* __restrict__ z1, const float4* __restrict__ z2,
    const float4* __restrict__ a,  const float4* __restrict__ b,
    float4* __restrict__ zi, int n4,
    const int* __restrict__ rows, const int* __restrict__ cols,
    const float* __restrict__ vals,
    int2* __restrict__ slots, int* __restrict__ cnt,
    int* __restrict__ ohead, int* __restrict__ onext,
    int cap, int E) {
  const int i = blockIdx.x * blockDim.x + threadIdx.x;
  const int stride = gridDim.x * blockDim.x;
  for (int j = i; j < n4; j += stride) {
    float4 A = a[j], B = b[j], X = z1[j], Y = z2[j];
    float4 z;
    z.x = A.x * X.x + B.x * Y.x;
    z.y = A.y * X.y + B.y * Y.y;
    z.z = A.z * X.z + B.z * Y.z;
    z.w = A.w * X.w + B.w * Y.w;
    zi[j] = z;
  }
  for (int e = i; e < E; e += stride) {
    const int r = rows[e];
    const int j = atomicAdd(&cnt[r], 1);
    if (j < cap) {
      int2 s;
      s.x = cols[e];
      s.y = __float_as_int(vals[e]);
      slots[(size_t)r * cap + j] = s;
    } else {
      onext[e] = atomicExch(&ohead[r], e);  // rare overflow
    }
  }
}

// One wave per row. Contiguous (col,val) metadata -> 4 independent gathers
// in flight per iteration. Residual blend fused into the single row write.
__global__ void __launch_bounds__(256) reduce_kernel(
    const int2* __restrict__ slots, const int* __restrict__ cnt,
    const int* __restrict__ ohead, const int* __restrict__ onext,
    const int* __restrict__ cols, const float* __restrict__ vals,
    const float* __restrict__ alpha_p,
    const float2* __restrict__ zi2, float2* __restrict__ out2,
    int cap, int N) {
  const int r = (int)((blockIdx.x * blockDim.x + threadIdx.x) >> 6);
  const int lane = threadIdx.x & 63;
  if (r >= N) return;
  const float alpha = alpha_p[0];

  const int deg = cnt[r];
  const int m = deg < cap ? deg : cap;
  const int2* sp = slots + (size_t)r * cap;
  const int4* sp4 = (const int4*)sp;   // cap even -> 16B-aligned rows

  float2 acc0 = make_float2(0.f, 0.f), acc1 = acc0, acc2 = acc0, acc3 = acc0;
  int j = 0;
  for (; j + 4 <= m; j += 4) {
    const int4 p0 = sp4[j >> 1];        // (col0,val0,col1,val1)
    const int4 p1 = sp4[(j >> 1) + 1];  // (col2,val2,col3,val3)
    const float2 g0 = zi2[(size_t)p0.x * (DDIM / 2) + lane];
    const float2 g1 = zi2[(size_t)p0.z * (DDIM / 2) + lane];
    const float2 g2 = zi2[(size_t)p1.x * (DDIM / 2) + lane];
    const float2 g3 = zi2[(size_t)p1.z * (DDIM / 2) + lane];
    const float v0 = __int_as_float(p0.y), v1 = __int_as_float(p0.w);
    const float v2 = __int_as_float(p1.y), v3 = __int_as_float(p1.w);
    acc0.x += v0 * g0.x; acc0.y += v0 * g0.y;
    acc1.x += v1 * g1.x; acc1.y += v1 * g1.y;
    acc2.x += v2 * g2.x; acc2.y += v2 * g2.y;
    acc3.x += v3 * g3.x; acc3.y += v3 * g3.y;
  }
  for (; j < m; ++j) {
    const int2 s = sp[j];
    const float v = __int_as_float(s.y);
    const float2 g = zi2[(size_t)s.x * (DDIM / 2) + lane];
    acc0.x += v * g.x; acc0.y += v * g.y;
  }
  if (deg > cap) {                       // overflow chain (rare / usually empty)
    int e = ohead[r];
    while (e >= 0) {
      const int en = onext[e];
      const int c = cols[e];
      const float v = vals[e];
      const float2 g = zi2[(size_t)c * (DDIM / 2) + lane];
      acc0.x += v * g.x; acc0.y += v * g.y;
      e = en;
    }
  }

  float2 acc;
  acc.x = (acc0.x + acc1.x) + (acc2.x + acc3.x);
  acc.y = (acc0.y + acc1.y) + (acc2.y + acc3.y);
  const float2 zr = zi2[(size_t)r * (DDIM / 2) + lane];
  const float om = 1.0f - alpha;
  float2 o;
  o.x = alpha * acc.x + om * zr.x;
  o.y = alpha * acc.y + om * zr.y;
  out2[(size_t)r * (DDIM / 2) + lane] = o;
}

extern "C" void kernel_launch(void* const* d_in, const int* in_sizes, int n_in,
                              void* d_out, int out_size, void* d_ws, size_t ws_size,
                              hipStream_t stream) {
  const float* z1    = (const float*)d_in[0];
  const float* z2    = (const float*)d_in[1];
  const int*   rows  = (const int*)  d_in[2];
  const int*   cols  = (const int*)  d_in[3];
  const float* vals  = (const float*)d_in[4];
  const float* a     = (const float*)d_in[5];
  const float* b     = (const float*)d_in[6];
  const float* alpha = (const float*)d_in[7];
  float* out = (float*)d_out;

  const int ND = in_sizes[0];            // N*D
  const int E  = in_sizes[2];
  const int N  = ND / DDIM;
  const int n4 = ND / 4;

  // ws layout: zi[ND] | cnt[N] | ohead[N] | onext[E] | slots[N*cap int2]
  float* zi  = (float*)d_ws;
  int* cnt   = (int*)(zi + ND);
  int* ohead = cnt + N;
  int* onext = ohead + N;
  int2* slots = (int2*)(onext + E);

  const size_t fixed_bytes = ((size_t)ND + 2 * N + E) * 4;
  size_t avail = ws_size > fixed_bytes ? ws_size - fixed_bytes : 0;
  int cap = (int)(avail / ((size_t)N * sizeof(int2)));
  if (cap > CAPMAX) cap = CAPMAX;
  cap &= ~1;                             // even -> int4-aligned slot rows
  if (cap < 2) cap = 0;

  hipMemsetAsync(cnt, 0x00, (size_t)N * sizeof(int), stream);
  hipMemsetAsync(ohead, 0xFF, (size_t)N * sizeof(int), stream);

  build_kernel<<<2048, 256, 0, stream>>>(
      (const float4*)z1, (const float4*)z2, (const float4*)a,
      (const float4*)b, (float4*)zi, n4,
      rows, cols, vals, slots, cnt, ohead, onext, cap, E);

  const int blocks2 = (int)(((long long)N * 64 + 255) / 256);
  reduce_kernel<<<blocks2, 256, 0, stream>>>(
      slots, cnt, ohead, onext, cols, vals, alpha,
      (const float2*)zi, (float2*)out, cap, N);
}

// Round 4
// 199.611 us; speedup vs baseline: 3.1766x; 1.0652x over previous
//
#include <hip/hip_runtime.h>
#include <hip/hip_fp16.h>

#define DDIM 128
#define CAPMAX 32

// Role-split build:
//   even blocks: zi = a*z1 + b*z2 -> zi32 (f32, for residual) + zi16 (f16, gather table)
//   odd  blocks: padded-CSR bin: j=atomicAdd(cnt[r]); j<cap -> slots[r*cap+j]=(col,val)
//                else overflow chain (ohead 0-sentinel, stores e+1)
// Splitting by block parity overlaps the BW-bound stream with the
// latency-bound scatter instead of running them back-to-back.
__global__ void __launch_bounds__(256) build_kernel(
    const float4* __restrict__ z1, const float4* __restrict__ z2,
    const float4* __restrict__ a,  const float4* __restrict__ b,
    float4* __restrict__ zi32, uint2* __restrict__ zi16, int n4,
    const int* __restrict__ rows, const int* __restrict__ cols,
    const float* __restrict__ vals,
    int2* __restrict__ slots, int* __restrict__ cnt,
    int* __restrict__ ohead, int* __restrict__ onext,
    int cap, int E) {
  const int t = (blockIdx.x >> 1) * blockDim.x + threadIdx.x;
  const int stride = (gridDim.x >> 1) * blockDim.x;
  if (blockIdx.x & 1) {
    for (int e = t; e < E; e += stride) {
      const int r = rows[e];
      const int j = atomicAdd(&cnt[r], 1);
      if (j < cap) {
        int2 s;
        s.x = cols[e];
        s.y = __float_as_int(vals[e]);
        slots[(size_t)r * cap + j] = s;
      } else {
        onext[e] = atomicExch(&ohead[r], e + 1);   // rare overflow
      }
    }
  } else {
    for (int j = t; j < n4; j += stride) {
      float4 A = a[j], B = b[j], X = z1[j], Y = z2[j];
      float4 z;
      z.x = A.x * X.x + B.x * Y.x;
      z.y = A.y * X.y + B.y * Y.y;
      z.z = A.z * X.z + B.z * Y.z;
      z.w = A.w * X.w + B.w * Y.w;
      zi32[j] = z;
      __half2 h0 = __floats2half2_rn(z.x, z.y);
      __half2 h1 = __floats2half2_rn(z.z, z.w);
      uint2 pk;
      pk.x = *reinterpret_cast<unsigned*>(&h0);
      pk.y = *reinterpret_cast<unsigned*>(&h1);
      zi16[j] = pk;
    }
  }
}

// One wave per row. 8 independent f16 gathers in flight per iteration.
// Residual blend reads the f32 table (only the message path carries f16 error).
__global__ void __launch_bounds__(256) reduce_kernel(
    const int2* __restrict__ slots, const int* __restrict__ cnt,
    const int* __restrict__ ohead, const int* __restrict__ onext,
    const int* __restrict__ cols, const float* __restrict__ vals,
    const float* __restrict__ alpha_p,
    const __half2* __restrict__ zi16, const float2* __restrict__ zi32,
    float2* __restrict__ out2, int cap, int N) {
  const int r = (int)((blockIdx.x * blockDim.x + threadIdx.x) >> 6);
  const int lane = threadIdx.x & 63;
  if (r >= N) return;
  const float alpha = alpha_p[0];

  const int deg = cnt[r];
  const int m = deg < cap ? deg : cap;
  const int2* sp = slots + (size_t)r * cap;
  const int4* sp4 = (const int4*)sp;       // cap even -> 16B-aligned rows

  float2 a0 = make_float2(0.f, 0.f), a1 = a0, a2 = a0, a3 = a0;
  float2 a4 = a0, a5 = a0, a6 = a0, a7 = a0;
  int j = 0;
  for (; j + 8 <= m; j += 8) {
    const int4 p0 = sp4[(j >> 1) + 0];
    const int4 p1 = sp4[(j >> 1) + 1];
    const int4 p2 = sp4[(j >> 1) + 2];
    const int4 p3 = sp4[(j >> 1) + 3];
    const __half2 g0 = zi16[(size_t)p0.x * (DDIM / 2) + lane];
    const __half2 g1 = zi16[(size_t)p0.z * (DDIM / 2) + lane];
    const __half2 g2 = zi16[(size_t)p1.x * (DDIM / 2) + lane];
    const __half2 g3 = zi16[(size_t)p1.z * (DDIM / 2) + lane];
    const __half2 g4 = zi16[(size_t)p2.x * (DDIM / 2) + lane];
    const __half2 g5 = zi16[(size_t)p2.z * (DDIM / 2) + lane];
    const __half2 g6 = zi16[(size_t)p3.x * (DDIM / 2) + lane];
    const __half2 g7 = zi16[(size_t)p3.z * (DDIM / 2) + lane];
    const float2 f0 = __half22float2(g0), f1 = __half22float2(g1);
    const float2 f2 = __half22float2(g2), f3 = __half22float2(g3);
    const float2 f4 = __half22float2(g4), f5 = __half22float2(g5);
    const float2 f6 = __half22float2(g6), f7 = __half22float2(g7);
    const float v0 = __int_as_float(p0.y), v1 = __int_as_float(p0.w);
    const float v2 = __int_as_float(p1.y), v3 = __int_as_float(p1.w);
    const float v4 = __int_as_float(p2.y), v5 = __int_as_float(p2.w);
    const float v6 = __int_as_float(p3.y), v7 = __int_as_float(p3.w);
    a0.x += v0 * f0.x; a0.y += v0 * f0.y;
    a1.x += v1 * f1.x; a1.y += v1 * f1.y;
    a2.x += v2 * f2.x; a2.y += v2 * f2.y;
    a3.x += v3 * f3.x; a3.y += v3 * f3.y;
    a4.x += v4 * f4.x; a4.y += v4 * f4.y;
    a5.x += v5 * f5.x; a5.y += v5 * f5.y;
    a6.x += v6 * f6.x; a6.y += v6 * f6.y;
    a7.x += v7 * f7.x; a7.y += v7 * f7.y;
  }
  for (; j < m; ++j) {
    const int2 s = sp[j];
    const float v = __int_as_float(s.y);
    const float2 f = __half22float2(zi16[(size_t)s.x * (DDIM / 2) + lane]);
    a0.x += v * f.x; a0.y += v * f.y;
  }
  if (deg > cap) {                          // overflow chain (rare)
    int e1 = ohead[r];
    while (e1 > 0) {
      const int e = e1 - 1;
      e1 = onext[e];
      const int c = cols[e];
      const float v = vals[e];
      const float2 f = __half22float2(zi16[(size_t)c * (DDIM / 2) + lane]);
      a0.x += v * f.x; a0.y += v * f.y;
    }
  }

  float2 acc;
  acc.x = ((a0.x + a1.x) + (a2.x + a3.x)) + ((a4.x + a5.x) + (a6.x + a7.x));
  acc.y = ((a0.y + a1.y) + (a2.y + a3.y)) + ((a4.y + a5.y) + (a6.y + a7.y));
  const float2 zr = zi32[(size_t)r * (DDIM / 2) + lane];
  const float om = 1.0f - alpha;
  float2 o;
  o.x = alpha * acc.x + om * zr.x;
  o.y = alpha * acc.y + om * zr.y;
  out2[(size_t)r * (DDIM / 2) + lane] = o;
}

extern "C" void kernel_launch(void* const* d_in, const int* in_sizes, int n_in,
                              void* d_out, int out_size, void* d_ws, size_t ws_size,
                              hipStream_t stream) {
  const float* z1    = (const float*)d_in[0];
  const float* z2    = (const float*)d_in[1];
  const int*   rows  = (const int*)  d_in[2];
  const int*   cols  = (const int*)  d_in[3];
  const float* vals  = (const float*)d_in[4];
  const float* a     = (const float*)d_in[5];
  const float* b     = (const float*)d_in[6];
  const float* alpha = (const float*)d_in[7];
  float* out = (float*)d_out;

  const int ND = in_sizes[0];              // N*D
  const int E  = in_sizes[2];
  const int N  = ND / DDIM;
  const int n4 = ND / 4;

  // ws: zi32[ND f32] | zi16[ND f16] | cnt[N] | ohead[N] | onext[E] | slots[N*cap int2]
  float* zi32 = (float*)d_ws;
  __half2* zi16 = (__half2*)(zi32 + ND);
  int* cnt   = (int*)((char*)zi16 + (size_t)ND * 2);
  int* ohead = cnt + N;
  int* onext = ohead + N;
  int2* slots = (int2*)(onext + E);

  const size_t fixed_bytes = (size_t)ND * 4 + (size_t)ND * 2 +
                             ((size_t)2 * N + E) * 4;
  size_t avail = ws_size > fixed_bytes ? ws_size - fixed_bytes : 0;
  int cap = (int)(avail / ((size_t)N * sizeof(int2)));
  if (cap > CAPMAX) cap = CAPMAX;
  cap &= ~1;                               // even -> int4-aligned slot rows
  if (cap < 2) cap = 0;

  // cnt=0 and ohead=0 (0-sentinel) in ONE memset
  hipMemsetAsync(cnt, 0x00, (size_t)2 * N * sizeof(int), stream);

  build_kernel<<<2048, 256, 0, stream>>>(
      (const float4*)z1, (const float4*)z2, (const float4*)a,
      (const float4*)b, (float4*)zi32, (uint2*)zi16, n4,
      rows, cols, vals, slots, cnt, ohead, onext, cap, E);

  const int blocks2 = (int)(((long long)N * 64 + 255) / 256);
  reduce_kernel<<<blocks2, 256, 0, stream>>>(
      slots, cnt, ohead, onext, cols, vals, alpha,
      zi16, (const float2*)zi32, (float2*)out, cap, N);
}